// Round 1
// baseline (417.492 us; speedup 1.0000x reference)
//
#include <hip/hip_runtime.h>

#define S_DIM 2048
#define D_DIM 64
#define EPS_PRE 1e-5f
#define EPS_NORM 1e-12f

typedef __attribute__((ext_vector_type(8))) short bf8;     // 8 x bf16 (bit pattern)
typedef __attribute__((ext_vector_type(4))) float f32x4;

static __device__ __forceinline__ unsigned fbits(float x){ union{float f;unsigned u;}v; v.f=x; return v.u; }
static __device__ __forceinline__ float bcast(unsigned u){ union{unsigned u;float f;}v; v.u=u; return v.f; }

// truncation split: x ~= hi + lo, both bf16-representable (top-16-bit truncation)
static __device__ __forceinline__ void split2(float x, unsigned short& h, unsigned short& l){
  unsigned u = fbits(x);
  h = (unsigned short)(u >> 16);
  float lo = x - bcast(u & 0xffff0000u);
  l = (unsigned short)(fbits(lo) >> 16);
}

// pack 4 floats into hi-pair / lo-pair uint2 (little-endian: .x low half = elem0)
static __device__ __forceinline__ void pack4f(float x0, float x1, float x2, float x3,
                                              uint2& hh, uint2& ll){
  unsigned u0=fbits(x0),u1=fbits(x1),u2=fbits(x2),u3=fbits(x3);
  hh.x = (u0>>16) | (u1 & 0xffff0000u);
  hh.y = (u2>>16) | (u3 & 0xffff0000u);
  float l0 = x0 - bcast(u0&0xffff0000u);
  float l1 = x1 - bcast(u1&0xffff0000u);
  float l2 = x2 - bcast(u2&0xffff0000u);
  float l3 = x3 - bcast(u3&0xffff0000u);
  ll.x = (fbits(l0)>>16) | (fbits(l1)&0xffff0000u);
  ll.y = (fbits(l2)>>16) | (fbits(l3)&0xffff0000u);
}

static __device__ __forceinline__ f32x4 mfma16(bf8 a, bf8 b, f32x4 c){
  return __builtin_amdgcn_mfma_f32_16x16x32_bf16(a, b, c, 0, 0, 0);
}

__global__ __launch_bounds__(256, 2)
void lka_fused(const float* __restrict__ Qg, const float* __restrict__ Kg,
               const float* __restrict__ Vg, float* __restrict__ Og,
               float* __restrict__ Ag)
{
  // K tile [64 t][64 d] bf16 hi/lo, V^T tile [64 d][64 t], P per-wave [4][16 s][64 t]
  __shared__ short kThi[4096], kTlo[4096];
  __shared__ short vThi[4096], vTlo[4096];
  __shared__ short pHi [4096], pLo [4096];

  const int tid = threadIdx.x;
  const int wv  = tid >> 6;     // wave 0..3 -> 16 s-rows each
  const int ln  = tid & 63;
  const int gq  = ln >> 4;      // lane group 0..3
  const int i16 = ln & 15;

  // block -> (bh, row-block) with heavy/light pairing (b and b+256) and bh XCD clustering
  const int blk = blockIdx.x;
  const int bh  = (blk & 7) | (((blk >> 3) & 1) << 3);
  const int qq  = blk >> 4;                 // 0..31
  const int rbk = (qq < 16) ? qq : 47 - qq; // row-block 0..31
  const int s0  = rbk * 64;

  const float* Qb = Qg + (size_t)bh * (S_DIM * D_DIM);
  const float* Kb = Kg + (size_t)bh * (S_DIM * D_DIM);
  const float* Vb = Vg + (size_t)bh * (S_DIM * D_DIM);
  float* Ob = Og + (size_t)bh * (S_DIM * D_DIM);
  float* Ab = Ag + (size_t)bh * ((size_t)S_DIM * S_DIM);

  const int srow = s0 + wv * 16 + i16;   // this lane's s (column of S^T tiles)

  // ---- persistent Q fragments (B operand: col=s=i16, k=d = ks*32+gq*8+j) ----
  bf8 qhi[2], qlo[2];
  #pragma unroll
  for (int ks = 0; ks < 2; ++ks) {
    const float* qp = Qb + (size_t)srow * D_DIM + ks * 32 + gq * 8;
    float4 a = *(const float4*)qp;
    float4 b = *(const float4*)(qp + 4);
    union { bf8 v; unsigned short h[8]; } H, L;
    float f0[8] = {a.x,a.y,a.z,a.w,b.x,b.y,b.z,b.w};
    #pragma unroll
    for (int j = 0; j < 8; ++j) split2(f0[j], H.h[j], L.h[j]);
    qhi[ks] = H.v; qlo[ks] = L.v;
  }

  // ---- zero-fill strictly-upper columns [ (rbk+1)*64, S ) for our 64 rows ----
  {
    const int c0 = (rbk + 1) * 64;
    const int n4 = (S_DIM - c0) >> 2;
    const int r  = tid >> 2;
    float* rowp = Ab + (size_t)(s0 + r) * S_DIM + c0;
    float4 z = make_float4(0.f, 0.f, 0.f, 0.f);
    for (int c = (tid & 3); c < n4; c += 4)
      *(float4*)(rowp + 4*c) = z;
  }

  // ---- staging helpers (256 threads cooperative) ----
  auto stageK = [&](int t0){
    const int t  = tid >> 2;
    const int db = (tid & 3) * 16;
    const float* kp = Kb + (size_t)(t0 + t) * D_DIM + db;
    #pragma unroll
    for (int c = 0; c < 4; ++c) {
      float4 kv = *(const float4*)(kp + 4*c);
      uint2 hh, ll; pack4f(kv.x, kv.y, kv.z, kv.w, hh, ll);
      const int idx = t*64 + ((db + 4*c) ^ ((t & 7) << 3));
      *(uint2*)&kThi[idx] = hh;
      *(uint2*)&kTlo[idx] = ll;
    }
  };
  auto stageV = [&](int t0){
    const int d  = (tid & 31) * 2;
    const int tb = (tid >> 5) * 8;
    float2 rr[8];
    #pragma unroll
    for (int k = 0; k < 8; ++k)
      rr[k] = *(const float2*)(Vb + (size_t)(t0 + tb + k) * D_DIM + d);
    #pragma unroll
    for (int dd = 0; dd < 2; ++dd) {
      union { bf8 v; unsigned short h[8]; } H, L;
      #pragma unroll
      for (int k = 0; k < 8; ++k) split2(dd ? rr[k].y : rr[k].x, H.h[k], L.h[k]);
      const int dc = d + dd;
      const int idx = dc*64 + (tb ^ ((dc & 7) << 3));
      *(bf8*)&vThi[idx] = H.v;
      *(bf8*)&vTlo[idx] = L.v;
    }
  };

  // S^T tile: acc[rf] rows t = t0+rf*16+gq*4+reg, col s = srow. 3-product split.
  auto qkstep = [&](f32x4* acc){
    #pragma unroll
    for (int rf = 0; rf < 4; ++rf) acc[rf] = (f32x4){0.f,0.f,0.f,0.f};
    #pragma unroll
    for (int ks = 0; ks < 2; ++ks) {
      #pragma unroll
      for (int rf = 0; rf < 4; ++rf) {
        const int t   = rf*16 + i16;
        const int idx = t*64 + ((ks*32 + gq*8) ^ ((t & 7) << 3));
        bf8 ahi = *(const bf8*)&kThi[idx];
        bf8 alo = *(const bf8*)&kTlo[idx];
        acc[rf] = mfma16(ahi, qhi[ks], acc[rf]);
        acc[rf] = mfma16(alo, qhi[ks], acc[rf]);
        acc[rf] = mfma16(ahi, qlo[ks], acc[rf]);
      }
    }
  };

  // ================= sweep 1: row norms =================
  float ssq = 0.f;
  for (int j = 0; j <= rbk; ++j) {
    __syncthreads();
    stageK(j * 64);
    __syncthreads();
    f32x4 acc[4];
    qkstep(acc);
    if (j == rbk) {
      #pragma unroll
      for (int rf = 0; rf < 4; ++rf)
        #pragma unroll
        for (int rg = 0; rg < 4; ++rg) {
          const int t = j*64 + rf*16 + gq*4 + rg;
          const float x = (t <= srow) ? (acc[rf][rg] + EPS_PRE) : 0.f;
          ssq += x * x;
        }
    } else {
      #pragma unroll
      for (int rf = 0; rf < 4; ++rf)
        #pragma unroll
        for (int rg = 0; rg < 4; ++rg) {
          const float x = acc[rf][rg] + EPS_PRE;
          ssq += x * x;
        }
    }
  }
  ssq += __shfl_xor(ssq, 16);
  ssq += __shfl_xor(ssq, 32);
  const float rinv = 1.f / fmaxf(sqrtf(ssq), EPS_NORM);

  // ================= sweep 2: emit attn + PV =================
  f32x4 oacc[4];
  #pragma unroll
  for (int rf = 0; rf < 4; ++rf) oacc[rf] = (f32x4){0.f,0.f,0.f,0.f};

  const int pR = wv*16 + i16;  // P row (s within block)

  for (int j = 0; j <= rbk; ++j) {
    __syncthreads();
    stageK(j * 64);
    stageV(j * 64);
    __syncthreads();

    f32x4 acc[4];
    qkstep(acc);

    #pragma unroll
    for (int rf = 0; rf < 4; ++rf) {
      f32x4 x;
      #pragma unroll
      for (int rg = 0; rg < 4; ++rg) {
        const int t = j*64 + rf*16 + gq*4 + rg;
        float v = acc[rf][rg] + EPS_PRE;
        if (j == rbk && t > srow) v = 0.f;
        x[rg] = v * rinv;
      }
      // stream normalized attn: row srow, 4 consecutive t
      *(f32x4*)(Ab + (size_t)srow * S_DIM + j*64 + rf*16 + gq*4) = x;
      // P (bf16 hi/lo) to per-wave LDS slice
      uint2 hh, ll; pack4f(x[0], x[1], x[2], x[3], hh, ll);
      const int pidx = pR*64 + ((rf*16 + gq*4) ^ ((pR & 7) << 3));
      *(uint2*)&pHi[pidx] = hh;
      *(uint2*)&pLo[pidx] = ll;
    }

    // PV: out^T = V^T (A) * P^T (B); k = t (64 = 2 ksteps)
    #pragma unroll
    for (int ks = 0; ks < 2; ++ks) {
      const int pi = pR*64 + ((ks*32 + gq*8) ^ ((pR & 7) << 3));
      bf8 bhi = *(const bf8*)&pHi[pi];
      bf8 blo = *(const bf8*)&pLo[pi];
      #pragma unroll
      for (int rfd = 0; rfd < 4; ++rfd) {
        const int dct = rfd*16 + i16;
        const int vi  = dct*64 + ((ks*32 + gq*8) ^ ((dct & 7) << 3));
        bf8 ahi = *(const bf8*)&vThi[vi];
        bf8 alo = *(const bf8*)&vTlo[vi];
        oacc[rfd] = mfma16(ahi, bhi, oacc[rfd]);
        oacc[rfd] = mfma16(alo, bhi, oacc[rfd]);
        oacc[rfd] = mfma16(ahi, blo, oacc[rfd]);
      }
    }
  }

  // out: lane col s=srow, rows d = rfd*16+gq*4+reg (4 consecutive d -> dwordx4)
  #pragma unroll
  for (int rfd = 0; rfd < 4; ++rfd)
    *(f32x4*)(Ob + (size_t)srow * D_DIM + rfd*16 + gq*4) = oacc[rfd];
}

extern "C" void kernel_launch(void* const* d_in, const int* in_sizes, int n_in,
                              void* d_out, int out_size, void* d_ws, size_t ws_size,
                              hipStream_t stream) {
  (void)in_sizes; (void)n_in; (void)out_size; (void)d_ws; (void)ws_size;
  const float* Q = (const float*)d_in[0];
  const float* K = (const float*)d_in[1];
  const float* V = (const float*)d_in[2];
  // d_in[3] is the causal mask (tril by construction) — applied analytically.
  float* out  = (float*)d_out;
  float* attn = out + (size_t)2 * 8 * 2048 * 64;
  lka_fused<<<dim3(512), dim3(256), 0, stream>>>(Q, K, V, out, attn);
}

// Round 2
// 388.359 us; speedup vs baseline: 1.0750x; 1.0750x over previous
//
#include <hip/hip_runtime.h>

#define S_DIM 2048
#define D_DIM 64
#define BH    16
#define EPS_PRE  1e-5f
#define EPS_NORM 1e-12f
#define CT 8   // t-tiles (64 cols each) per chunk-block

typedef __attribute__((ext_vector_type(8))) short bf8;     // 8 x bf16 (bit pattern)
typedef __attribute__((ext_vector_type(4))) float f32x4;

static __device__ __forceinline__ unsigned fbits(float x){ union{float f;unsigned u;}v; v.f=x; return v.u; }
static __device__ __forceinline__ float bcast(unsigned u){ union{unsigned u;float f;}v; v.u=u; return v.f; }

// truncation split: x ~= hi + lo, both bf16-representable
static __device__ __forceinline__ void split2(float x, unsigned short& h, unsigned short& l){
  unsigned u = fbits(x);
  h = (unsigned short)(u >> 16);
  float lo = x - bcast(u & 0xffff0000u);
  l = (unsigned short)(fbits(lo) >> 16);
}

static __device__ __forceinline__ void pack4f(float x0, float x1, float x2, float x3,
                                              uint2& hh, uint2& ll){
  unsigned u0=fbits(x0),u1=fbits(x1),u2=fbits(x2),u3=fbits(x3);
  hh.x = (u0>>16) | (u1 & 0xffff0000u);
  hh.y = (u2>>16) | (u3 & 0xffff0000u);
  float l0 = x0 - bcast(u0&0xffff0000u);
  float l1 = x1 - bcast(u1&0xffff0000u);
  float l2 = x2 - bcast(u2&0xffff0000u);
  float l3 = x3 - bcast(u3&0xffff0000u);
  ll.x = (fbits(l0)>>16) | (fbits(l1)&0xffff0000u);
  ll.y = (fbits(l2)>>16) | (fbits(l3)&0xffff0000u);
}

static __device__ __forceinline__ f32x4 mfma16(bf8 a, bf8 b, f32x4 c){
  return __builtin_amdgcn_mfma_f32_16x16x32_bf16(a, b, c, 0, 0, 0);
}

// chunk id c in [0,80) -> (row-block rb 0..31, chunk ck, nchunks nk for this rb)
static __device__ __forceinline__ void decode(int c, int& rb, int& ck, int& nk){
  int g = 0;
  while (c >= 4*(g+1)*(g+2)) ++g;       // g = rb>>3 in 0..3
  const int off = c - 4*g*(g+1);
  nk = g + 1;
  const int q = off / nk;
  rb = g*8 + q;
  ck = off - q*nk;
}

// ======================= K1: row norms (+ upper-triangle zeros) =======================
__global__ __launch_bounds__(256, 4)
void lka_norm(const float* __restrict__ Qg, const float* __restrict__ Kg,
              float* __restrict__ ssqg, float* __restrict__ Ag)
{
  __shared__ short kThi[4096], kTlo[4096];

  const int tid = threadIdx.x;
  const int wv  = tid >> 6;
  const int ln  = tid & 63;
  const int gq  = ln >> 4;
  const int i16 = ln & 15;

  const int blk = blockIdx.x;
  const int bh  = blk & 15;
  int rb, ck, nk; decode(blk >> 4, rb, ck, nk);
  const int s0 = rb * 64;

  const float* Qb = Qg + (size_t)bh * (S_DIM * D_DIM);
  const float* Kb = Kg + (size_t)bh * (S_DIM * D_DIM);
  float* Ab = Ag + (size_t)bh * ((size_t)S_DIM * S_DIM);

  const int srow = s0 + wv * 16 + i16;

  // ---- balanced zero-fill of a slice of this row-block's upper triangle ----
  {
    const int zt0 = (rb + 1) + ((31 - rb) * ck) / nk;
    const int zt1 = (rb + 1) + ((31 - rb) * (ck + 1)) / nk;
    if (zt1 > zt0) {
      const int r = tid >> 2;
      float4* rowp = (float4*)(Ab + (size_t)(s0 + r) * S_DIM + zt0 * 64);
      const int n4 = (zt1 - zt0) * 16;
      float4 z = make_float4(0.f, 0.f, 0.f, 0.f);
      for (int c4 = tid & 3; c4 < n4; c4 += 4) rowp[c4] = z;
    }
  }

  // ---- persistent Q fragments ----
  bf8 qhi[2], qlo[2];
  #pragma unroll
  for (int ks = 0; ks < 2; ++ks) {
    const float* qp = Qb + (size_t)srow * D_DIM + ks * 32 + gq * 8;
    float4 a = *(const float4*)qp;
    float4 b = *(const float4*)(qp + 4);
    union { bf8 v; unsigned short h[8]; } H, L;
    float f0[8] = {a.x,a.y,a.z,a.w,b.x,b.y,b.z,b.w};
    #pragma unroll
    for (int j = 0; j < 8; ++j) split2(f0[j], H.h[j], L.h[j]);
    qhi[ks] = H.v; qlo[ks] = L.v;
  }

  auto stageK = [&](int t0){
    const int t  = tid >> 2;
    const int db = (tid & 3) * 16;
    const float* kp = Kb + (size_t)(t0 + t) * D_DIM + db;
    #pragma unroll
    for (int c = 0; c < 4; ++c) {
      float4 kv = *(const float4*)(kp + 4*c);
      uint2 hh, ll; pack4f(kv.x, kv.y, kv.z, kv.w, hh, ll);
      const int idx = t*64 + ((db + 4*c) ^ ((t & 7) << 3));
      *(uint2*)&kThi[idx] = hh;
      *(uint2*)&kTlo[idx] = ll;
    }
  };

  auto qkstep = [&](f32x4* acc){
    #pragma unroll
    for (int rf = 0; rf < 4; ++rf) acc[rf] = (f32x4){0.f,0.f,0.f,0.f};
    #pragma unroll
    for (int ks = 0; ks < 2; ++ks) {
      #pragma unroll
      for (int rf = 0; rf < 4; ++rf) {
        const int t   = rf*16 + i16;
        const int idx = t*64 + ((ks*32 + gq*8) ^ ((t & 7) << 3));
        bf8 ahi = *(const bf8*)&kThi[idx];
        bf8 alo = *(const bf8*)&kTlo[idx];
        acc[rf] = mfma16(ahi, qhi[ks], acc[rf]);
        acc[rf] = mfma16(alo, qhi[ks], acc[rf]);
        acc[rf] = mfma16(ahi, qlo[ks], acc[rf]);
      }
    }
  };

  float ssq = 0.f;
  const int j0 = ck * CT;
  const int j1 = min(j0 + CT, rb + 1);
  for (int j = j0; j < j1; ++j) {
    __syncthreads();
    stageK(j * 64);
    __syncthreads();
    f32x4 acc[4];
    qkstep(acc);
    if (j == rb) {
      #pragma unroll
      for (int rf = 0; rf < 4; ++rf)
        #pragma unroll
        for (int rg = 0; rg < 4; ++rg) {
          const int t = j*64 + rf*16 + gq*4 + rg;
          const float x = (t <= srow) ? (acc[rf][rg] + EPS_PRE) : 0.f;
          ssq += x * x;
        }
    } else {
      #pragma unroll
      for (int rf = 0; rf < 4; ++rf)
        #pragma unroll
        for (int rg = 0; rg < 4; ++rg) {
          const float x = acc[rf][rg] + EPS_PRE;
          ssq += x * x;
        }
    }
  }
  ssq += __shfl_xor(ssq, 16);
  ssq += __shfl_xor(ssq, 32);
  if (gq == 0)
    atomicAdd(&ssqg[bh * S_DIM + srow], ssq);
}

// ======================= K2: scale + stream attn + PV partials =======================
__global__ __launch_bounds__(256, 3)
void lka_emit(const float* __restrict__ Qg, const float* __restrict__ Kg,
              const float* __restrict__ Vg, const float* __restrict__ ssqg,
              float* __restrict__ Og, float* __restrict__ Ag)
{
  __shared__ short kThi[4096], kTlo[4096];
  __shared__ short vThi[4096], vTlo[4096];
  __shared__ short pHi [4096], pLo [4096];

  const int tid = threadIdx.x;
  const int wv  = tid >> 6;
  const int ln  = tid & 63;
  const int gq  = ln >> 4;
  const int i16 = ln & 15;

  const int blk = blockIdx.x;
  const int bh  = blk & 15;
  int rb, ck, nk; decode(blk >> 4, rb, ck, nk);
  (void)nk;
  const int s0 = rb * 64;

  const float* Qb = Qg + (size_t)bh * (S_DIM * D_DIM);
  const float* Kb = Kg + (size_t)bh * (S_DIM * D_DIM);
  const float* Vb = Vg + (size_t)bh * (S_DIM * D_DIM);
  float* Ob = Og + (size_t)bh * (S_DIM * D_DIM);
  float* Ab = Ag + (size_t)bh * ((size_t)S_DIM * S_DIM);

  const int srow = s0 + wv * 16 + i16;

  // row norm is complete (K1 finished at kernel boundary)
  const float rinv = 1.f / fmaxf(sqrtf(ssqg[bh * S_DIM + srow]), EPS_NORM);

  // ---- persistent Q fragments ----
  bf8 qhi[2], qlo[2];
  #pragma unroll
  for (int ks = 0; ks < 2; ++ks) {
    const float* qp = Qb + (size_t)srow * D_DIM + ks * 32 + gq * 8;
    float4 a = *(const float4*)qp;
    float4 b = *(const float4*)(qp + 4);
    union { bf8 v; unsigned short h[8]; } H, L;
    float f0[8] = {a.x,a.y,a.z,a.w,b.x,b.y,b.z,b.w};
    #pragma unroll
    for (int j = 0; j < 8; ++j) split2(f0[j], H.h[j], L.h[j]);
    qhi[ks] = H.v; qlo[ks] = L.v;
  }

  auto stageK = [&](int t0){
    const int t  = tid >> 2;
    const int db = (tid & 3) * 16;
    const float* kp = Kb + (size_t)(t0 + t) * D_DIM + db;
    #pragma unroll
    for (int c = 0; c < 4; ++c) {
      float4 kv = *(const float4*)(kp + 4*c);
      uint2 hh, ll; pack4f(kv.x, kv.y, kv.z, kv.w, hh, ll);
      const int idx = t*64 + ((db + 4*c) ^ ((t & 7) << 3));
      *(uint2*)&kThi[idx] = hh;
      *(uint2*)&kTlo[idx] = ll;
    }
  };
  auto stageV = [&](int t0){
    const int d  = (tid & 31) * 2;
    const int tb = (tid >> 5) * 8;
    float2 rr[8];
    #pragma unroll
    for (int k = 0; k < 8; ++k)
      rr[k] = *(const float2*)(Vb + (size_t)(t0 + tb + k) * D_DIM + d);
    #pragma unroll
    for (int dd = 0; dd < 2; ++dd) {
      union { bf8 v; unsigned short h[8]; } H, L;
      #pragma unroll
      for (int k = 0; k < 8; ++k) split2(dd ? rr[k].y : rr[k].x, H.h[k], L.h[k]);
      const int dc = d + dd;
      const int idx = dc*64 + (tb ^ ((dc & 7) << 3));
      *(bf8*)&vThi[idx] = H.v;
      *(bf8*)&vTlo[idx] = L.v;
    }
  };

  auto qkstep = [&](f32x4* acc){
    #pragma unroll
    for (int rf = 0; rf < 4; ++rf) acc[rf] = (f32x4){0.f,0.f,0.f,0.f};
    #pragma unroll
    for (int ks = 0; ks < 2; ++ks) {
      #pragma unroll
      for (int rf = 0; rf < 4; ++rf) {
        const int t   = rf*16 + i16;
        const int idx = t*64 + ((ks*32 + gq*8) ^ ((t & 7) << 3));
        bf8 ahi = *(const bf8*)&kThi[idx];
        bf8 alo = *(const bf8*)&kTlo[idx];
        acc[rf] = mfma16(ahi, qhi[ks], acc[rf]);
        acc[rf] = mfma16(alo, qhi[ks], acc[rf]);
        acc[rf] = mfma16(ahi, qlo[ks], acc[rf]);
      }
    }
  };

  f32x4 oacc[4];
  #pragma unroll
  for (int rf = 0; rf < 4; ++rf) oacc[rf] = (f32x4){0.f,0.f,0.f,0.f};

  const int pR = wv*16 + i16;

  const int j0 = ck * CT;
  const int j1 = min(j0 + CT, rb + 1);
  for (int j = j0; j < j1; ++j) {
    __syncthreads();
    stageK(j * 64);
    stageV(j * 64);
    __syncthreads();

    f32x4 acc[4];
    qkstep(acc);

    #pragma unroll
    for (int rf = 0; rf < 4; ++rf) {
      f32x4 x;
      #pragma unroll
      for (int rg = 0; rg < 4; ++rg) {
        const int t = j*64 + rf*16 + gq*4 + rg;
        float v = acc[rf][rg] + EPS_PRE;
        if (j == rb && t > srow) v = 0.f;
        x[rg] = v * rinv;
      }
      *(f32x4*)(Ab + (size_t)srow * S_DIM + j*64 + rf*16 + gq*4) = x;
      uint2 hh, ll; pack4f(x[0], x[1], x[2], x[3], hh, ll);
      const int pidx = pR*64 + ((rf*16 + gq*4) ^ ((pR & 7) << 3));
      *(uint2*)&pHi[pidx] = hh;
      *(uint2*)&pLo[pidx] = ll;
    }

    #pragma unroll
    for (int ks = 0; ks < 2; ++ks) {
      const int pi = pR*64 + ((ks*32 + gq*8) ^ ((pR & 7) << 3));
      bf8 bhi = *(const bf8*)&pHi[pi];
      bf8 blo = *(const bf8*)&pLo[pi];
      #pragma unroll
      for (int rfd = 0; rfd < 4; ++rfd) {
        const int dct = rfd*16 + i16;
        const int vi  = dct*64 + ((ks*32 + gq*8) ^ ((dct & 7) << 3));
        bf8 ahi = *(const bf8*)&vThi[vi];
        bf8 alo = *(const bf8*)&vTlo[vi];
        oacc[rfd] = mfma16(ahi, bhi, oacc[rfd]);
        oacc[rfd] = mfma16(alo, bhi, oacc[rfd]);
        oacc[rfd] = mfma16(ahi, blo, oacc[rfd]);
      }
    }
  }

  // accumulate PV partial into (pre-zeroed) out
  #pragma unroll
  for (int rfd = 0; rfd < 4; ++rfd)
    #pragma unroll
    for (int rg = 0; rg < 4; ++rg)
      atomicAdd(&Ob[(size_t)srow * D_DIM + rfd*16 + gq*4 + rg], oacc[rfd][rg]);
}

extern "C" void kernel_launch(void* const* d_in, const int* in_sizes, int n_in,
                              void* d_out, int out_size, void* d_ws, size_t ws_size,
                              hipStream_t stream) {
  (void)in_sizes; (void)n_in; (void)out_size; (void)ws_size;
  const float* Q = (const float*)d_in[0];
  const float* K = (const float*)d_in[1];
  const float* V = (const float*)d_in[2];
  float* out  = (float*)d_out;
  float* attn = out + (size_t)BH * S_DIM * D_DIM;
  float* ssq  = (float*)d_ws;

  hipMemsetAsync(ssq, 0, (size_t)BH * S_DIM * sizeof(float), stream);
  hipMemsetAsync(out, 0, (size_t)BH * S_DIM * D_DIM * sizeof(float), stream);

  const int nblk = BH * 80;   // 80 causal chunks per (b,h)
  lka_norm<<<dim3(nblk), dim3(256), 0, stream>>>(Q, K, ssq, attn);
  lka_emit<<<dim3(nblk), dim3(256), 0, stream>>>(Q, K, V, ssq, out, attn);
}